// Round 6
// baseline (256.050 us; speedup 1.0000x reference)
//
#include <hip/hip_runtime.h>
#include <math.h>

// Hasegawa-Wakatani 2D RHS, 2048^2, all-spectral. Round 6:
//  - corner-turn moved from writer stores (R5: 16B scatter, 1.8x write amp,
//    105us kernel) to reader loads (64B/32B segment gathers):
//      unpack stores row-major coalesced; bracket/final are 4-x-column slab
//      kernels; mask pass is a plain row kernel.
// 5 dispatches, ~536 MB logical traffic, every access >= 32B segments.
//
// Pipeline:
//  pack_T    : n,w [x][y] --fftY, write^T--> W[ky][x]              (ws0)
//  unpack_inv: W row-pair --fftX, unpack, 4x ifftX--> TTA=(T1,T2)[ky][x],
//              T3[ky][x], T4[ky][x]   (all coalesced rows)
//  bracket   : 4-x slab of TTA/T3 --3x ifftKY, j, fftY--> BR[ky'][x]
//  maskrow   : BR row --fftX, 2/3 mask /N, ifftX--> ADV[ky'][x]
//  final     : 4-x slab of ADV,T4 --2x ifftKY, combine--> dn,dw [x][y]

#define NF 2048
#define HALF 1024
#define K0F 0.15f
#define DEAL_LIM 682

typedef float2 cplx;

__device__ __forceinline__ int sw(int i){ return i ^ ((i>>4)&15) ^ ((i>>8)&15); }
__device__ __forceinline__ cplx cmul(cplx a, cplx b){ return make_float2(a.x*b.x - a.y*b.y, a.x*b.y + a.y*b.x); }
__device__ __forceinline__ cplx cadd(cplx a, cplx b){ return make_float2(a.x+b.x, a.y+b.y); }
__device__ __forceinline__ cplx csub(cplx a, cplx b){ return make_float2(a.x-b.x, a.y-b.y); }
template<int SIGN> __device__ __forceinline__ cplx rot90(cplx z){
  return (SIGN>0)? make_float2(-z.y,z.x) : make_float2(z.y,-z.x); }
__device__ __forceinline__ void lput(cplx* L, int i, cplx v){ L[sw(i)] = v; }
__device__ __forceinline__ cplx lget(const cplx* L, int i){ return L[sw(i)]; }

// chunked XCD swizzle (grid % 8 == 0): consecutive logical blocks -> same XCD
__device__ __forceinline__ int xcd_chunk(int bid, int nwg){
  return (bid & 7) * (nwg >> 3) + (bid >> 3);
}

// ---- in-place radix-8 stage: read all, barrier, write all, barrier.
template<int SIGN, int TPR, int M>
__device__ __forceinline__ void stage8_ip(cplx* X, int t) {
  constexpr int BPT = 256 / TPR;
  const float ang = (float)SIGN * 0.0030679615757712824f; // 2*pi/2048
  cplx a[BPT][8];
#pragma unroll
  for (int u = 0; u < BPT; ++u) {
    const int b = t + u * TPR;
#pragma unroll
    for (int k = 0; k < 8; ++k) a[u][k] = X[sw(b + 256 * k)];
  }
  __syncthreads();
#pragma unroll
  for (int u = 0; u < BPT; ++u) {
    const int b = t + u * TPR;
    const int i = b & (M - 1);
    const int jm = b - i;
    cplx a0=a[u][0], a1=a[u][1], a2=a[u][2], a3=a[u][3],
         a4=a[u][4], a5=a[u][5], a6=a[u][6], a7=a[u][7];
    cplx t0=cadd(a0,a4), t1=csub(a0,a4), t2=cadd(a2,a6), t3=rot90<SIGN>(csub(a2,a6));
    cplx E0=cadd(t0,t2), E2=csub(t0,t2), E1=cadd(t1,t3), E3=csub(t1,t3);
    cplx u0=cadd(a1,a5), u1=csub(a1,a5), u2=cadd(a3,a7), u3=rot90<SIGN>(csub(a3,a7));
    cplx O0=cadd(u0,u2), O2=csub(u0,u2), O1=cadd(u1,u3), O3=csub(u1,u3);
    const float hh = 0.70710678118654752440f;
    O1 = cmul(O1, make_float2(hh, (float)SIGN*hh));
    O2 = rot90<SIGN>(O2);
    O3 = cmul(O3, make_float2(-hh, (float)SIGN*hh));
    cplx y0=cadd(E0,O0), y4=csub(E0,O0);
    cplx y1=cadd(E1,O1), y5=csub(E1,O1);
    cplx y2=cadd(E2,O2), y6=csub(E2,O2);
    cplx y3=cadd(E3,O3), y7=csub(E3,O3);
    float sn, cs;
    __sincosf(ang * (float)jm, &sn, &cs);
    cplx w1 = make_float2(cs, sn);
    cplx w2 = cmul(w1,w1), w3 = cmul(w2,w1), w4 = cmul(w2,w2);
    cplx w5 = cmul(w3,w2), w6 = cmul(w3,w3), w7 = cmul(w4,w3);
    const int o = 8*jm + i;
    X[sw(o)]       = y0;
    X[sw(o+M)]     = cmul(y1,w1);
    X[sw(o+2*M)]   = cmul(y2,w2);
    X[sw(o+3*M)]   = cmul(y3,w3);
    X[sw(o+4*M)]   = cmul(y4,w4);
    X[sw(o+5*M)]   = cmul(y5,w5);
    X[sw(o+6*M)]   = cmul(y6,w6);
    X[sw(o+7*M)]   = cmul(y7,w7);
  }
  __syncthreads();
}

template<int SIGN, int TPR>
__device__ __forceinline__ void stage4_ip(cplx* X, int t){
  constexpr int QPT = 512 / TPR;
  cplx a[QPT][4];
#pragma unroll
  for (int u=0; u<QPT; ++u){
    const int b = t + u*TPR;
#pragma unroll
    for (int k=0;k<4;++k) a[u][k] = X[sw(b + 512*k)];
  }
  __syncthreads();
#pragma unroll
  for (int u=0; u<QPT; ++u){
    const int b = t + u*TPR;
    cplx a0=a[u][0], a1=a[u][1], a2=a[u][2], a3=a[u][3];
    cplx t0=cadd(a0,a2), t1=csub(a0,a2), t2=cadd(a1,a3), t3=rot90<SIGN>(csub(a1,a3));
    X[sw(b)]       = cadd(t0,t2);
    X[sw(b+512)]   = cadd(t1,t3);
    X[sw(b+1024)]  = csub(t0,t2);
    X[sw(b+1536)]  = csub(t1,t3);
  }
  __syncthreads();
}

// entry barrier covers caller's LDS fill; exits with results published.
template<int SIGN, int TPR>
__device__ __forceinline__ void fft_ip(cplx* X, int t){
  __syncthreads();
  stage8_ip<SIGN,TPR,1>(X,t);
  stage8_ip<SIGN,TPR,8>(X,t);
  stage8_ip<SIGN,TPR,64>(X,t);
  stage4_ip<SIGN,TPR>(X,t);
}

// ---- spectral unpack: one of the 4 packed spectra at one (kx,ky) point.
template<int I>
__device__ __forceinline__ cplx unpack_one(cplx a, cplx b,
    float kxv, float kyv, float kxp, float kyp) {
  cplx nh = make_float2(0.5f*(a.x + b.x),  0.5f*(a.y - b.y));
  cplx wh = make_float2(0.5f*(a.y + b.y), -0.5f*(a.x - b.x));
  float k2 = kxv*kxv + kyv*kyv;
  if constexpr (I == 0) {
    float pinv = (k2 > 1e-12f) ? (-1.0f/k2) : 0.0f;
    cplx ph = make_float2(wh.x*pinv, wh.y*pinv);
    return make_float2(-kxp*ph.y - kyp*ph.x, kxp*ph.x - kyp*ph.y);
  } else if constexpr (I == 1) {
    return make_float2(-kxp*nh.y - kyp*nh.x, kxp*nh.x - kyp*nh.y);
  } else if constexpr (I == 2) {
    return make_float2(-kxp*wh.y - kyp*wh.x, kxp*wh.x - kyp*wh.y);
  } else {
    float pinv = (k2 > 1e-12f) ? (-1.0f/k2) : 0.0f;
    cplx ph = make_float2(wh.x*pinv, wh.y*pinv);
    float dnc = 0.001f * k2;
    cplx Ln = make_float2( kyp*ph.y + (ph.x - nh.x) - dnc*nh.x,
                          -kyp*ph.x + (ph.y - nh.y) - dnc*nh.y);
    cplx Lw = make_float2( kyp*nh.y + (ph.x - nh.x) - dnc*wh.x,
                          -kyp*nh.x + (ph.y - nh.y) - dnc*wh.y);
    return make_float2(Ln.x - Lw.y, Ln.y + Lw.x);
  }
}

template<int I>
__device__ __forceinline__ void build_spec(cplx* Wm, const cplx* Fm, const cplx* Fp,
                                           int t, float kyv, float kyp) {
#pragma unroll
  for (int u=0; u<8; ++u){
    int kx = t + u*256;
    int kx2 = (NF - kx) & (NF - 1);
    int sx = (kx < HALF) ? kx : kx - NF;
    float kxv = K0F * (float)sx;
    float kxp = (kx == HALF) ? 0.0f : kxv;
    lput(Wm, kx, unpack_one<I>(lget(Fm, kx), lget(Fp, kx2), kxv, kyv, kxp, kyp));
  }
}

// ---- kernels -------------------------------------------------------------

// 4 x-rows: load n,w, fft along y, transposed store -> out[ky][x]
__global__ void __launch_bounds__(512) k_fwd_pack_T(const float* __restrict__ nIn,
                                                    const float* __restrict__ wIn,
                                                    cplx* __restrict__ out) {
  __shared__ cplx L[4*NF];
  const int tid = threadIdx.x;
  const int lb = xcd_chunk(blockIdx.x, gridDim.x);
  const int xb = lb*4;
#pragma unroll
  for (int u=0; u<4; ++u){
    int f = tid + u*512;           // 0..2047
    int r = f >> 9;                // row 0..3
    int p = f & 511;               // float4 idx
    float4 nv = ((const float4*)(nIn + (size_t)(xb+r)*NF))[p];
    float4 wv = ((const float4*)(wIn + (size_t)(xb+r)*NF))[p];
    cplx* Lr = L + r*NF;
    lput(Lr, 4*p+0, make_float2(nv.x, wv.x));
    lput(Lr, 4*p+1, make_float2(nv.y, wv.y));
    lput(Lr, 4*p+2, make_float2(nv.z, wv.z));
    lput(Lr, 4*p+3, make_float2(nv.w, wv.w));
  }
  const int row = tid >> 7, t = tid & 127;
  fft_ip<-1,128>(L + row*NF, t);
  float4* o4 = (float4*)out;
#pragma unroll
  for (int u=0; u<8; ++u){
    int f = tid + u*512;           // 0..4095
    int ky = f >> 1;
    int xp = f & 1;                // local x-pair
    cplx a = lget(L + (2*xp)*NF, ky);
    cplx b = lget(L + (2*xp+1)*NF, ky);
    o4[(size_t)ky*(NF/2) + lb*2 + xp] = make_float4(a.x,a.y,b.x,b.y);
  }
}

// row-pair (ky, NF-ky): fftX both, unpack 4 spectra, ifftX each, store
// row-major coalesced: TTA[ky][x]=(T1,T2) float4; T3[ky][x], T4[ky][x] cplx.
__global__ void __launch_bounds__(512) k_unpack_inv(const cplx* __restrict__ in,
                                                    float4* __restrict__ TTA,
                                                    cplx* __restrict__ T3,
                                                    cplx* __restrict__ T4) {
  __shared__ cplx F0[NF], F1[NF], W0[NF], W1[NF];
  const int tid = threadIdx.x;
  const int b = xcd_chunk(blockIdx.x, gridDim.x);   // 0..1023
  const int kyA = b;
  const int kyB = (b == 0) ? HALF : NF - b;
  const int half = tid >> 8;
  const int t = tid & 255;
  cplx* Fm = half ? F1 : F0;
  {
    const cplx* g = in + (size_t)(half ? kyB : kyA)*NF;
#pragma unroll
    for (int u=0; u<4; ++u){
      int p = t + u*256;
      float4 v = ((const float4*)g)[p];
      lput(Fm, 2*p,   make_float2(v.x,v.y));
      lput(Fm, 2*p+1, make_float2(v.z,v.w));
    }
    fft_ip<-1,256>(Fm, t);
  }
  // conj-mirror partner row: for b=0 each row is self-paired
  const cplx* Fp = (b == 0) ? (const cplx*)Fm : (half ? F0 : F1);
  cplx* Wm = half ? W1 : W0;
  const int kyM = half ? kyB : kyA;
  const int sy = (kyM < HALF) ? kyM : kyM - NF;
  const float kyv = K0F * (float)sy;
  const float kyp = (kyM == HALF) ? 0.0f : kyv;
  const float sc = 1.0f/(float)NF;
  const size_t rbase = (size_t)kyM * NF;
  cplx r[8];

  // S1 -> regs
  build_spec<0>(Wm, Fm, Fp, t, kyv, kyp);
  fft_ip<1,256>(Wm, t);
#pragma unroll
  for (int u=0; u<8; ++u) r[u] = lget(Wm, t + u*256);
  // S2 -> store (T1,T2) row, coalesced
  build_spec<1>(Wm, Fm, Fp, t, kyv, kyp);
  fft_ip<1,256>(Wm, t);
#pragma unroll
  for (int u=0; u<8; ++u){
    int x = t + u*256;
    cplx z = lget(Wm, x);
    TTA[rbase + x] = make_float4(sc*r[u].x, sc*r[u].y, sc*z.x, sc*z.y);
  }
  // S3 -> store T3 row
  build_spec<2>(Wm, Fm, Fp, t, kyv, kyp);
  fft_ip<1,256>(Wm, t);
#pragma unroll
  for (int u=0; u<8; ++u){
    int x = t + u*256;
    cplx z = lget(Wm, x);
    T3[rbase + x] = make_float2(sc*z.x, sc*z.y);
  }
  // S4 -> store T4 row
  build_spec<3>(Wm, Fm, Fp, t, kyv, kyp);
  fft_ip<1,256>(Wm, t);
#pragma unroll
  for (int u=0; u<8; ++u){
    int x = t + u*256;
    cplx z = lget(Wm, x);
    T4[rbase + x] = make_float2(sc*z.x, sc*z.y);
  }
}

// 4-x-column slab: gather TTA (64B segs) / T3 (32B segs) columns,
// 3x ifft along ky (dphi,jn in regs; T2 re-read from L2-hot TTA),
// bracket, fwd fft -> BR[ky'][x] (32B segs).
__global__ void __launch_bounds__(512) k_bracket(const float4* __restrict__ TTA,
                                                 const cplx* __restrict__ T3,
                                                 cplx* __restrict__ BR) {
  __shared__ cplx W[4*NF];   // 64 KB: column j at W + j*NF
  const int tid = threadIdx.x;
  const int lb = xcd_chunk(blockIdx.x, gridDim.x);  // 0..511
  const int x0 = lb*4;
  // load 1: T1 halves of TTA slab
#pragma unroll
  for (int u=0; u<16; ++u){
    int f = tid + u*512;          // 0..8191 = ky*4 + j
    int ky = f >> 2, j = f & 3;
    float4 v = TTA[(size_t)ky*NF + x0 + j];
    lput(W + j*NF, ky, make_float2(v.x, v.y));
  }
  const int col = tid >> 7, t = tid & 127;
  cplx* Wc = W + col*NF;
  fft_ip<1,128>(Wc, t);                   // (dphix,dphiy)*N per column
  cplx dphi[16];
#pragma unroll
  for (int u=0; u<16; ++u) dphi[u] = lget(Wc, t + u*128);
  __syncthreads();
  // load 2: T2 halves (TTA re-read; L2-hot)
#pragma unroll
  for (int u=0; u<16; ++u){
    int f = tid + u*512;
    int ky = f >> 2, j = f & 3;
    float4 v = TTA[(size_t)ky*NF + x0 + j];
    lput(W + j*NF, ky, make_float2(v.z, v.w));
  }
  fft_ip<1,128>(Wc, t);                   // (dnx,dny)*N
  float jn[16];
#pragma unroll
  for (int u=0; u<16; ++u){
    cplx dd = lget(Wc, t + u*128);
    jn[u] = dphi[u].x*dd.y - dphi[u].y*dd.x;
  }
  __syncthreads();
  // load 3: T3 slab
#pragma unroll
  for (int u=0; u<16; ++u){
    int f = tid + u*512;
    int ky = f >> 2, j = f & 3;
    lput(W + j*NF, ky, T3[(size_t)ky*NF + x0 + j]);
  }
  fft_ip<1,128>(Wc, t);                   // (dwx,dwy)*N
  const float sc2 = 1.0f/((float)NF*(float)NF);
#pragma unroll
  for (int u=0; u<16; ++u){
    int c = t + u*128;
    cplx dd = lget(Wc, c);
    float jw = dphi[u].x*dd.y - dphi[u].y*dd.x;
    lput(Wc, c, make_float2(sc2*jn[u], sc2*jw));   // own-slot r/w
  }
  fft_ip<-1,128>(Wc, t);                  // fft(j_n + i*j_w) along y
  // store BR slab [ky'][x0+j], 32B segs
#pragma unroll
  for (int u=0; u<16; ++u){
    int f = tid + u*512;
    int ky = f >> 2, j = f & 3;
    BR[(size_t)ky*NF + x0 + j] = lget(W + j*NF, ky);
  }
}

// row kernel: BR[ky'] row --fftX, 2/3 mask * (1/N), ifftX--> ADV[ky'] row
__global__ void __launch_bounds__(256) k_maskrow(const cplx* __restrict__ in,
                                                 cplx* __restrict__ out) {
  __shared__ cplx A[NF];
  const int t = threadIdx.x;
  const int row = blockIdx.x;    // = ky'
  const size_t base = (size_t)row * NF;
#pragma unroll
  for (int u=0; u<4; ++u){
    int p = t + u*256;
    float4 v = ((const float4*)(in + base))[p];
    lput(A, 2*p,   make_float2(v.x,v.y));
    lput(A, 2*p+1, make_float2(v.z,v.w));
  }
  fft_ip<-1,256>(A, t);
  const int sy = (row < HALF) ? row : row - NF;
  const float my = ((sy < 0 ? -sy : sy) <= DEAL_LIM) ? 1.0f : 0.0f;
  const float sc = 1.0f/(float)NF;
#pragma unroll
  for (int u=0; u<8; ++u){
    int kk = t + u*256;
    int sx = (kk < HALF) ? kk : kk - NF;
    float m = (my != 0.0f && ((sx<0?-sx:sx) <= DEAL_LIM)) ? sc : 0.0f;
    cplx z = lget(A, kk);
    lput(A, kk, make_float2(m*z.x, m*z.y));       // own-slot r/w
  }
  fft_ip<1,256>(A, t);
  float4* o4 = (float4*)(out + base);
#pragma unroll
  for (int u=0; u<4; ++u){
    int p = t + u*256;
    cplx a = lget(A, 2*p), b = lget(A, 2*p+1);
    o4[p] = make_float4(a.x,a.y,b.x,b.y);
  }
}

// 4-x-column slab: ifft ADV columns (park in regs), ifft T4 columns,
// combine -> dn,dw rows (coalesced)
__global__ void __launch_bounds__(512) k_final(const cplx* __restrict__ ADV,
                                               const cplx* __restrict__ T4,
                                               float* __restrict__ outF) {
  __shared__ cplx W[4*NF];
  const int tid = threadIdx.x;
  const int lb = xcd_chunk(blockIdx.x, gridDim.x);  // 0..511
  const int x0 = lb*4;
#pragma unroll
  for (int u=0; u<16; ++u){
    int f = tid + u*512;
    int ky = f >> 2, j = f & 3;
    lput(W + j*NF, ky, ADV[(size_t)ky*NF + x0 + j]);
  }
  const int col = tid >> 7, t = tid & 127;
  cplx* Wc = W + col*NF;
  fft_ip<1,128>(Wc, t);                   // adv*N
  cplx adv[16];
#pragma unroll
  for (int u=0; u<16; ++u) adv[u] = lget(Wc, t + u*128);
  __syncthreads();
#pragma unroll
  for (int u=0; u<16; ++u){
    int f = tid + u*512;
    int ky = f >> 2, j = f & 3;
    lput(W + j*NF, ky, T4[(size_t)ky*NF + x0 + j]);
  }
  fft_ip<1,128>(Wc, t);                   // (Ln,Lw)*N
  const float sc = 1.0f/(float)NF;
  const size_t NSQ = (size_t)NF*NF;
  const size_t obase = (size_t)(x0 + col) * NF;
#pragma unroll
  for (int u=0; u<16; ++u){
    int c = t + u*128;
    cplx Lv = lget(Wc, c);
    outF[obase + c]       = sc*(Lv.x - adv[u].x);   // dn
    outF[NSQ + obase + c] = sc*(Lv.y - adv[u].y);   // dw
  }
}

extern "C" void kernel_launch(void* const* d_in, const int* in_sizes, int n_in,
                              void* d_out, int out_size, void* d_ws, size_t ws_size,
                              hipStream_t stream) {
  const float* nIn = (const float*)d_in[0];
  const float* wIn = (const float*)d_in[1];
  float* outF = (float*)d_out;

  const size_t B = (size_t)NF * NF * sizeof(cplx);   // 33.5 MB
  char* ws = (char*)d_ws;
  cplx*   ws0 = (cplx*)(ws);               // W, later BR
  float4* TTA = (float4*)(ws + 1*B);       // (T1,T2) interleaved: 2 slots
  cplx*   ADV = (cplx*)(ws + 1*B);         // reuses TTA region after bracket
  cplx*   T3  = (cplx*)(ws + 3*B);
  cplx*   T4  = (cplx*)(ws + 4*B);

  // forward pass 1 (along y) with transposed store
  k_fwd_pack_T <<<512, 512, 0, stream>>>(nIn, wIn, ws0);        // W[ky][x]

  // forward pass 2 + unpack + inverse pass 1, row-major coalesced stores
  k_unpack_inv <<<1024, 512, 0, stream>>>(ws0, TTA, T3, T4);

  // bracket: slab-gather columns, 3x ifftY + j + fwd fftY -> BR[ky'][x]
  k_bracket <<<512, 512, 0, stream>>>(TTA, T3, ws0);

  // dealias row pass: fftX + mask/N + ifftX -> ADV[ky'][x] (overwrites TTA)
  k_maskrow <<<NF, 256, 0, stream>>>(ws0, ADV);

  // final: slab-gather ADV,T4 columns, 2x ifftY, combine -> d_out
  k_final <<<512, 512, 0, stream>>>(ADV, T4, outF);
}

// Round 7
// 184.937 us; speedup vs baseline: 1.3845x; 1.3845x over previous
//
#include <hip/hip_runtime.h>
#include <hip/hip_fp16.h>
#include <math.h>

// Hasegawa-Wakatani 2D RHS, 2048^2, all-spectral. Round 7 = R4 structure
// (best measured: 205us) + traffic cuts:
//  - S1..S4 intermediates in fp16 (__half2 per cplx), pre-scaled 1/N at
//    unpack (avoids fp16 overflow of k*n_hat ~ 1.7e5). Both sides of the
//    S round-trip are coalesced rows -> halving is pattern-risk-free.
//  - dealias-aware skips: bracket doesn't store the masked middle third of
//    BR rows; slabX write-zeros fast path for fully-masked slabs.
//  - unpack b-scheme: 1024 blocks, 32KB LDS, no mirror double-stores.
// 7 dispatches, ~630 MB logical traffic.
//
// Pipeline (slots of 33.5MB in d_ws):
//  pack_T : n,w --fftY, write^T--> W[ky][x]                     slot0
//  unpackS: W row --fftX, unpack--> S1..S4 (fp16, 1/N)          slot1,2
//  inv2 x2: S_i --ifftX, write^T--> T_i [x][ky] f32   T1,T2->slot3,4; T3,T4->slot0,1
//  bracket: T1..T3 rows --3x ifftY, j, fftY, my-skip--> BR      d_out
//  slabX  : BR --fftX, mask/N, ifftX, write^T-->  ADVt          slot2
//  final  : ADVt,T4 rows --2x ifftY, combine--> dn,dw           d_out

#define NF 2048
#define HALF 1024
#define K0F 0.15f
#define DEAL_LIM 682

typedef float2 cplx;
typedef __half2 ch;

__device__ __forceinline__ ch toh(cplx v){ return __float22half2_rn(make_float2(v.x, v.y)); }
__device__ __forceinline__ cplx toc(ch h){ float2 f = __half22float2(h); return make_float2(f.x, f.y); }

__device__ __forceinline__ int sw(int i){ return i ^ ((i>>4)&15) ^ ((i>>8)&15); }
__device__ __forceinline__ cplx cmul(cplx a, cplx b){ return make_float2(a.x*b.x - a.y*b.y, a.x*b.y + a.y*b.x); }
__device__ __forceinline__ cplx cadd(cplx a, cplx b){ return make_float2(a.x+b.x, a.y+b.y); }
__device__ __forceinline__ cplx csub(cplx a, cplx b){ return make_float2(a.x-b.x, a.y-b.y); }
template<int SIGN> __device__ __forceinline__ cplx rot90(cplx z){
  return (SIGN>0)? make_float2(-z.y,z.x) : make_float2(z.y,-z.x); }
__device__ __forceinline__ void lput(cplx* L, int i, cplx v){ L[sw(i)] = v; }
__device__ __forceinline__ cplx lget(const cplx* L, int i){ return L[sw(i)]; }

__device__ __forceinline__ int xcd_chunk(int bid, int nwg){
  return (bid & 7) * (nwg >> 3) + (bid >> 3);
}

// ---- in-place radix-8 stage: read all, barrier, write all, barrier.
template<int SIGN, int TPR, int M>
__device__ __forceinline__ void stage8_ip(cplx* X, int t) {
  constexpr int BPT = 256 / TPR;
  const float ang = (float)SIGN * 0.0030679615757712824f; // 2*pi/2048
  cplx a[BPT][8];
#pragma unroll
  for (int u = 0; u < BPT; ++u) {
    const int b = t + u * TPR;
#pragma unroll
    for (int k = 0; k < 8; ++k) a[u][k] = X[sw(b + 256 * k)];
  }
  __syncthreads();
#pragma unroll
  for (int u = 0; u < BPT; ++u) {
    const int b = t + u * TPR;
    const int i = b & (M - 1);
    const int jm = b - i;
    cplx a0=a[u][0], a1=a[u][1], a2=a[u][2], a3=a[u][3],
         a4=a[u][4], a5=a[u][5], a6=a[u][6], a7=a[u][7];
    cplx t0=cadd(a0,a4), t1=csub(a0,a4), t2=cadd(a2,a6), t3=rot90<SIGN>(csub(a2,a6));
    cplx E0=cadd(t0,t2), E2=csub(t0,t2), E1=cadd(t1,t3), E3=csub(t1,t3);
    cplx u0=cadd(a1,a5), u1=csub(a1,a5), u2=cadd(a3,a7), u3=rot90<SIGN>(csub(a3,a7));
    cplx O0=cadd(u0,u2), O2=csub(u0,u2), O1=cadd(u1,u3), O3=csub(u1,u3);
    const float hh = 0.70710678118654752440f;
    O1 = cmul(O1, make_float2(hh, (float)SIGN*hh));
    O2 = rot90<SIGN>(O2);
    O3 = cmul(O3, make_float2(-hh, (float)SIGN*hh));
    cplx y0=cadd(E0,O0), y4=csub(E0,O0);
    cplx y1=cadd(E1,O1), y5=csub(E1,O1);
    cplx y2=cadd(E2,O2), y6=csub(E2,O2);
    cplx y3=cadd(E3,O3), y7=csub(E3,O3);
    float sn, cs;
    __sincosf(ang * (float)jm, &sn, &cs);
    cplx w1 = make_float2(cs, sn);
    cplx w2 = cmul(w1,w1), w3 = cmul(w2,w1), w4 = cmul(w2,w2);
    cplx w5 = cmul(w3,w2), w6 = cmul(w3,w3), w7 = cmul(w4,w3);
    const int o = 8*jm + i;
    X[sw(o)]       = y0;
    X[sw(o+M)]     = cmul(y1,w1);
    X[sw(o+2*M)]   = cmul(y2,w2);
    X[sw(o+3*M)]   = cmul(y3,w3);
    X[sw(o+4*M)]   = cmul(y4,w4);
    X[sw(o+5*M)]   = cmul(y5,w5);
    X[sw(o+6*M)]   = cmul(y6,w6);
    X[sw(o+7*M)]   = cmul(y7,w7);
  }
  __syncthreads();
}

template<int SIGN, int TPR>
__device__ __forceinline__ void stage4_ip(cplx* X, int t){
  constexpr int QPT = 512 / TPR;
  cplx a[QPT][4];
#pragma unroll
  for (int u=0; u<QPT; ++u){
    const int b = t + u*TPR;
#pragma unroll
    for (int k=0;k<4;++k) a[u][k] = X[sw(b + 512*k)];
  }
  __syncthreads();
#pragma unroll
  for (int u=0; u<QPT; ++u){
    const int b = t + u*TPR;
    cplx a0=a[u][0], a1=a[u][1], a2=a[u][2], a3=a[u][3];
    cplx t0=cadd(a0,a2), t1=csub(a0,a2), t2=cadd(a1,a3), t3=rot90<SIGN>(csub(a1,a3));
    X[sw(b)]       = cadd(t0,t2);
    X[sw(b+512)]   = cadd(t1,t3);
    X[sw(b+1024)]  = csub(t0,t2);
    X[sw(b+1536)]  = csub(t1,t3);
  }
  __syncthreads();
}

template<int SIGN, int TPR>
__device__ __forceinline__ void fft_ip(cplx* X, int t){
  __syncthreads();
  stage8_ip<SIGN,TPR,1>(X,t);
  stage8_ip<SIGN,TPR,8>(X,t);
  stage8_ip<SIGN,TPR,64>(X,t);
  stage4_ip<SIGN,TPR>(X,t);
}

// ---- spectral unpack at one (kx,ky): a=F(ky,kx), b=F(-ky,-kx)
__device__ __forceinline__ void unpack_point(cplx a, cplx b,
    float kxv, float kyv, float kxp, float kyp,
    cplx& s1, cplx& s2, cplx& s3, cplx& s4) {
  cplx nh = make_float2(0.5f*(a.x + b.x),  0.5f*(a.y - b.y));
  cplx wh = make_float2(0.5f*(a.y + b.y), -0.5f*(a.x - b.x));
  float k2 = kxv*kxv + kyv*kyv;
  float pinv = (k2 > 1e-12f) ? (-1.0f/k2) : 0.0f;
  cplx ph = make_float2(wh.x*pinv, wh.y*pinv);
  s1 = make_float2(-kxp*ph.y - kyp*ph.x, kxp*ph.x - kyp*ph.y);
  s2 = make_float2(-kxp*nh.y - kyp*nh.x, kxp*nh.x - kyp*nh.y);
  s3 = make_float2(-kxp*wh.y - kyp*wh.x, kxp*wh.x - kyp*wh.y);
  float dnc = 0.001f * k2;
  cplx Ln = make_float2( kyp*ph.y + (ph.x - nh.x) - dnc*nh.x,
                        -kyp*ph.x + (ph.y - nh.y) - dnc*nh.y);
  cplx Lw = make_float2( kyp*nh.y + (ph.x - nh.x) - dnc*wh.x,
                        -kyp*nh.x + (ph.y - nh.y) - dnc*wh.y);
  s4 = make_float2(Ln.x - Lw.y, Ln.y + Lw.x);
}

// ---- kernels -------------------------------------------------------------

// 4 x-rows: load n,w, fft along y, transposed store -> out[ky][x] (f32)
__global__ void __launch_bounds__(512) k_fwd_pack_T(const float* __restrict__ nIn,
                                                    const float* __restrict__ wIn,
                                                    cplx* __restrict__ out) {
  __shared__ cplx L[4*NF];
  const int tid = threadIdx.x;
  const int lb = xcd_chunk(blockIdx.x, gridDim.x);
  const int xb = lb*4;
#pragma unroll
  for (int u=0; u<4; ++u){
    int f = tid + u*512;           // 0..2047
    int r = f >> 9;                // row 0..3
    int p = f & 511;               // float4 idx
    float4 nv = ((const float4*)(nIn + (size_t)(xb+r)*NF))[p];
    float4 wv = ((const float4*)(wIn + (size_t)(xb+r)*NF))[p];
    cplx* Lr = L + r*NF;
    lput(Lr, 4*p+0, make_float2(nv.x, wv.x));
    lput(Lr, 4*p+1, make_float2(nv.y, wv.y));
    lput(Lr, 4*p+2, make_float2(nv.z, wv.z));
    lput(Lr, 4*p+3, make_float2(nv.w, wv.w));
  }
  const int row = tid >> 7, t = tid & 127;
  fft_ip<-1,128>(L + row*NF, t);
  float4* o4 = (float4*)out;
#pragma unroll
  for (int u=0; u<8; ++u){
    int f = tid + u*512;           // 0..4095
    int ky = f >> 1;
    int xp = f & 1;
    cplx a = lget(L + (2*xp)*NF, ky);
    cplx b = lget(L + (2*xp+1)*NF, ky);
    o4[(size_t)ky*(NF/2) + lb*2 + xp] = make_float4(a.x,a.y,b.x,b.y);
  }
}

// rows kyA=b, kyB=(b==0?1024:2048-b): fftX both, unpack -> S1..S4 fp16 rows
// (pre-scaled by 1/N).
__global__ void __launch_bounds__(512) k_unpackS(const cplx* __restrict__ in,
                                                 ch* __restrict__ S1, ch* __restrict__ S2,
                                                 ch* __restrict__ S3, ch* __restrict__ S4) {
  __shared__ cplx F0[NF], F1[NF];
  const int tid = threadIdx.x;
  const int b = xcd_chunk(blockIdx.x, gridDim.x);   // 0..1023
  const int kyA = b;
  const int kyB = (b == 0) ? HALF : NF - b;
  const int half = tid >> 8;
  const int t = tid & 255;
  cplx* Fm = half ? F1 : F0;
  {
    const cplx* g = in + (size_t)(half ? kyB : kyA)*NF;
#pragma unroll
    for (int u=0; u<4; ++u){
      int p = t + u*256;
      float4 v = ((const float4*)g)[p];
      lput(Fm, 2*p,   make_float2(v.x,v.y));
      lput(Fm, 2*p+1, make_float2(v.z,v.w));
    }
    fft_ip<-1,256>(Fm, t);
  }
  // partner row for conj-mirror; b=0: rows 0 and 1024 are self-paired
  const cplx* Fp = (b == 0) ? (const cplx*)Fm : (half ? F0 : F1);
  const int kyM = half ? kyB : kyA;
  const int sy = (kyM < HALF) ? kyM : kyM - NF;
  const float kyv = K0F * (float)sy;
  const float kyp = (kyM == HALF) ? 0.0f : kyv;
  const float sc = 1.0f/(float)NF;
  const size_t rbase = (size_t)kyM * NF;
#pragma unroll
  for (int u=0; u<8; ++u){
    int kx = t + u*256;
    int kx2 = (NF - kx) & (NF - 1);
    int sx = (kx < HALF) ? kx : kx - NF;
    float kxv = K0F * (float)sx;
    float kxp = (kx == HALF) ? 0.0f : kxv;
    cplx s1,s2,s3,s4;
    unpack_point(lget(Fm,kx), lget(Fp,kx2), kxv, kyv, kxp, kyp, s1,s2,s3,s4);
    S1[rbase+kx] = toh(make_float2(sc*s1.x, sc*s1.y));
    S2[rbase+kx] = toh(make_float2(sc*s2.x, sc*s2.y));
    S3[rbase+kx] = toh(make_float2(sc*s3.x, sc*s3.y));
    S4[rbase+kx] = toh(make_float2(sc*s4.x, sc*s4.y));
  }
}

// 4 rows x 2 arrays: ifft along contiguous dim (input fp16, pre-scaled),
// transposed store f32 -> T[x][ky] (32B segs)
__global__ void __launch_bounds__(512) k_inv2(const ch* __restrict__ in0,
                                              const ch* __restrict__ in1,
                                              cplx* __restrict__ out0,
                                              cplx* __restrict__ out1) {
  __shared__ cplx L[4*NF];
  const int tid = threadIdx.x;
  const int lb = xcd_chunk(blockIdx.x, gridDim.x);
  const ch* in = blockIdx.y ? in1 : in0;
  cplx* out = blockIdx.y ? out1 : out0;
  const int rb = lb*4;
#pragma unroll
  for (int u=0; u<4; ++u){
    int f = tid + u*512;           // 0..2047
    int r = f >> 9, p = f & 511;   // 512 uint4 per fp16 row (16B = 4 cplx16)
    uint4 v = ((const uint4*)(in + (size_t)(rb+r)*NF))[p];
    cplx* Lr = L + r*NF;
    lput(Lr, 4*p+0, toc(*(ch*)&v.x));
    lput(Lr, 4*p+1, toc(*(ch*)&v.y));
    lput(Lr, 4*p+2, toc(*(ch*)&v.z));
    lput(Lr, 4*p+3, toc(*(ch*)&v.w));
  }
  const int row = tid >> 7, t = tid & 127;
  fft_ip<1,128>(L + row*NF, t);
  float4* o4 = (float4*)out;
#pragma unroll
  for (int u=0; u<8; ++u){
    int f = tid + u*512;
    int q = f >> 1;                // transposed output row
    int xp = f & 1;
    cplx a = lget(L + (2*xp)*NF, q);
    cplx b = lget(L + (2*xp+1)*NF, q);
    o4[(size_t)q*(NF/2) + lb*2 + xp] = make_float4(a.x,a.y,b.x,b.y);
  }
}

// 1 x-row: 3x ifft along ky (dphi in regs), bracket, fwd fft -> BR[x][ky'],
// skipping stores of the my-masked middle third.
__global__ void __launch_bounds__(256) k_bracket(const cplx* __restrict__ T1,
                                                 const cplx* __restrict__ T2,
                                                 const cplx* __restrict__ T3,
                                                 cplx* __restrict__ out) {
  __shared__ cplx A[NF];
  const int t = threadIdx.x;
  const size_t base = (size_t)blockIdx.x * NF;
#pragma unroll
  for (int u=0; u<4; ++u){
    int p = t + u*256;
    float4 v = ((const float4*)(T1 + base))[p];
    lput(A, 2*p, make_float2(v.x,v.y)); lput(A, 2*p+1, make_float2(v.z,v.w));
  }
  fft_ip<1,256>(A, t);                  // (dphix,dphiy)*N
  cplx dphi[8];
#pragma unroll
  for (int u=0; u<8; ++u) dphi[u] = lget(A, t + u*256);
  __syncthreads();
#pragma unroll
  for (int u=0; u<4; ++u){
    int p = t + u*256;
    float4 v = ((const float4*)(T2 + base))[p];
    lput(A, 2*p, make_float2(v.x,v.y)); lput(A, 2*p+1, make_float2(v.z,v.w));
  }
  fft_ip<1,256>(A, t);                  // (dnx,dny)*N
  float jn[8];
#pragma unroll
  for (int u=0; u<8; ++u){
    cplx dd = lget(A, t + u*256);
    jn[u] = dphi[u].x*dd.y - dphi[u].y*dd.x;
  }
  __syncthreads();
#pragma unroll
  for (int u=0; u<4; ++u){
    int p = t + u*256;
    float4 v = ((const float4*)(T3 + base))[p];
    lput(A, 2*p, make_float2(v.x,v.y)); lput(A, 2*p+1, make_float2(v.z,v.w));
  }
  fft_ip<1,256>(A, t);                  // (dwx,dwy)*N
  const float sc2 = 1.0f/((float)NF*(float)NF);
#pragma unroll
  for (int u=0; u<8; ++u){
    int c = t + u*256;
    cplx dd = lget(A, c);
    float jw = dphi[u].x*dd.y - dphi[u].y*dd.x;
    lput(A, c, make_float2(sc2*jn[u], sc2*jw));   // own-slot r/w
  }
  fft_ip<-1,256>(A, t);                 // fft(j_n + i*j_w) along y
  float4* o4 = (float4*)(out + base);
#pragma unroll
  for (int u=0; u<4; ++u){
    int p = t + u*256;                  // pair (2p, 2p+1) of ky'
    if (p <= 341 || p >= 683) {         // skip pairs fully inside mask [683,1365]
      cplx a = lget(A, 2*p), b = lget(A, 2*p+1);
      o4[p] = make_float4(a.x,a.y,b.x,b.y);
    }
  }
}

// 4 ky'-columns: fftX, 2/3 mask * (1/N), ifftX, transposed write [x][ky'].
// Fully-masked slabs: write zeros, no reads/FFTs.
__global__ void __launch_bounds__(512) k_slabX(const cplx* __restrict__ in,
                                               cplx* __restrict__ out) {
  __shared__ cplx L[4*NF];
  const int tid = threadIdx.x;
  const int lb = xcd_chunk(blockIdx.x, gridDim.x);
  const int cb = lb*4;
  if (cb >= 684 && cb <= 1360) {        // all 4 ky' in masked band
    const float4 z = make_float4(0.f,0.f,0.f,0.f);
#pragma unroll
    for (int u=0; u<8; ++u){
      int f = tid + u*512;
      int x = f >> 1, j = f & 1;
      ((float4*)(out + (size_t)x*NF + cb))[j] = z;
    }
    return;
  }
#pragma unroll
  for (int u=0; u<8; ++u){
    int f = tid + u*512;           // 0..4095
    int x = f >> 1, j = f & 1;
    float4 v = ((const float4*)(in + (size_t)x*NF + cb))[j];
    lput(L + (2*j)*NF,   x, make_float2(v.x,v.y));
    lput(L + (2*j+1)*NF, x, make_float2(v.z,v.w));
  }
  const int row = tid >> 7, t = tid & 127;
  fft_ip<-1,128>(L + row*NF, t);
  const float sc = 1.0f/(float)NF;
#pragma unroll
  for (int v2=0; v2<16; ++v2){
    int g = tid + v2*512;          // 0..8191
    int c = g >> 11, kk = g & 2047;
    int ky = cb + c;
    int sy = (ky < HALF) ? ky : ky - NF;
    int sx = (kk < HALF) ? kk : kk - NF;
    float m = (((sy<0?-sy:sy) <= DEAL_LIM) && ((sx<0?-sx:sx) <= DEAL_LIM)) ? sc : 0.0f;
    cplx z = lget(L + c*NF, kk);
    lput(L + c*NF, kk, make_float2(m*z.x, m*z.y));   // own-slot r/w
  }
  fft_ip<1,128>(L + row*NF, t);
#pragma unroll
  for (int u=0; u<8; ++u){
    int f = tid + u*512;
    int x = f >> 1, j = f & 1;
    cplx a = lget(L + (2*j)*NF, x);
    cplx b = lget(L + (2*j+1)*NF, x);
    ((float4*)(out + (size_t)x*NF + cb))[j] = make_float4(a.x,a.y,b.x,b.y);
  }
}

// 1 x-row: ifft ADVt (adv in regs), ifft T4, combine -> dn,dw
__global__ void __launch_bounds__(256) k_final(const cplx* __restrict__ ADVt,
                                               const cplx* __restrict__ T4,
                                               float* __restrict__ outF) {
  __shared__ cplx A[NF];
  const int t = threadIdx.x;
  const size_t base = (size_t)blockIdx.x * NF;
#pragma unroll
  for (int u=0; u<4; ++u){
    int p = t + u*256;
    float4 v = ((const float4*)(ADVt + base))[p];
    lput(A, 2*p, make_float2(v.x,v.y)); lput(A, 2*p+1, make_float2(v.z,v.w));
  }
  fft_ip<1,256>(A, t);                  // adv*N
  cplx adv[8];
#pragma unroll
  for (int u=0; u<8; ++u) adv[u] = lget(A, t + u*256);
  __syncthreads();
#pragma unroll
  for (int u=0; u<4; ++u){
    int p = t + u*256;
    float4 v = ((const float4*)(T4 + base))[p];
    lput(A, 2*p, make_float2(v.x,v.y)); lput(A, 2*p+1, make_float2(v.z,v.w));
  }
  fft_ip<1,256>(A, t);                  // (Ln,Lw)*N
  const float sc = 1.0f/(float)NF;
  const size_t NSQ = (size_t)NF*NF;
#pragma unroll
  for (int u=0; u<8; ++u){
    int c = t + u*256;
    cplx Lv = lget(A, c);
    outF[base + c]       = sc*(Lv.x - adv[u].x);   // dn
    outF[NSQ + base + c] = sc*(Lv.y - adv[u].y);   // dw
  }
}

extern "C" void kernel_launch(void* const* d_in, const int* in_sizes, int n_in,
                              void* d_out, int out_size, void* d_ws, size_t ws_size,
                              hipStream_t stream) {
  const float* nIn = (const float*)d_in[0];
  const float* wIn = (const float*)d_in[1];
  float* outF = (float*)d_out;

  const size_t B = (size_t)NF * NF * sizeof(cplx);     // 33.5 MB
  const size_t Bh = (size_t)NF * NF * sizeof(ch);      // 16.75 MB
  char* ws = (char*)d_ws;
  cplx* W    = (cplx*)(ws);                 // slot0: W, then T3
  ch*   S1   = (ch*)(ws + 1*B);             // slot1: S1,S2 -> later T4
  ch*   S2   = (ch*)(ws + 1*B + Bh);
  ch*   S3   = (ch*)(ws + 2*B);             // slot2: S3,S4 -> later ADVt
  ch*   S4   = (ch*)(ws + 2*B + Bh);
  cplx* T1   = (cplx*)(ws + 3*B);           // slot3
  cplx* T2   = (cplx*)(ws + 4*B);           // slot4
  cplx* T3   = (cplx*)(ws);                 // slot0 (W dead after unpackS)
  cplx* T4   = (cplx*)(ws + 1*B);           // slot1 (S1,S2 dead after inv2 #1)
  cplx* ADVt = (cplx*)(ws + 2*B);           // slot2 (S3,S4 dead after inv2 #2)
  cplx* BR   = (cplx*)d_out;                // scratch until k_final overwrites

  // forward pass 1 (along y) with transposed store
  k_fwd_pack_T <<<512, 512, 0, stream>>>(nIn, wIn, W);

  // forward pass 2 + unpack -> S1..S4 (fp16, 1/N)
  k_unpackS <<<1024, 512, 0, stream>>>(W, S1, S2, S3, S4);

  // ifft along kx + transposed store
  k_inv2 <<<dim3(512,2), 512, 0, stream>>>(S1, S2, T1, T2);
  k_inv2 <<<dim3(512,2), 512, 0, stream>>>(S3, S4, T3, T4);

  // bracket (finishes ifftY) + fwd fftY -> BR [x][ky'] (masked rows skipped)
  k_bracket <<<NF, 256, 0, stream>>>(T1, T2, T3, BR);

  // fftX + dealias + ifftX fused, transposed write -> ADVt [x][ky']
  k_slabX <<<512, 512, 0, stream>>>(BR, ADVt);

  // final: ifftY of ADVt & T4, combine -> d_out
  k_final <<<NF, 256, 0, stream>>>(ADVt, T4, outF);
}

// Round 8
// 173.820 us; speedup vs baseline: 1.4731x; 1.0640x over previous
//
#include <hip/hip_runtime.h>
#include <hip/hip_fp16.h>
#include <math.h>

// Hasegawa-Wakatani 2D RHS, 2048^2, all-spectral. Round 8 = R7 +
// fp16 for ALL intermediates after the W stage:
//  - T1..T4 fp16 (inv2 writes 16B segments, dense + XCD-chunked)
//  - BR fp16 (coalesced rows, masked-third skipped on both sides)
//  - ADVt fp16 (slabX writes one uint4 per x per block)
//  - W stays f32 (feeds everything; error budget caution)
// 7 dispatches, ~525 MB traffic.
//
// Pipeline (slots of 33.5MB in d_ws):
//  pack_T : n,w --fftY, write^T--> W[ky][x] f32                 slot0
//  unpackS: W row --fftX, unpack--> S1..S4 (fp16, 1/N)          slot1,2
//  inv2 x2: S_i --ifftX, write^T--> T_i [x][ky] fp16   T1,T2->slot3; T3,T4->slot4
//  bracket: T1..T3 rows --3x ifftY, j, fftY, my-skip--> BR fp16 d_out
//  slabX  : BR --fftX, mask/N, ifftX, write^T--> ADVt fp16      slot1
//  final  : ADVt,T4 rows --2x ifftY, combine--> dn,dw f32       d_out

#define NF 2048
#define HALF 1024
#define K0F 0.15f
#define DEAL_LIM 682

typedef float2 cplx;
typedef __half2 ch;

__device__ __forceinline__ ch toh(cplx v){ return __float22half2_rn(make_float2(v.x, v.y)); }
__device__ __forceinline__ cplx toc(ch h){ float2 f = __half22float2(h); return make_float2(f.x, f.y); }

__device__ __forceinline__ int sw(int i){ return i ^ ((i>>4)&15) ^ ((i>>8)&15); }
__device__ __forceinline__ cplx cmul(cplx a, cplx b){ return make_float2(a.x*b.x - a.y*b.y, a.x*b.y + a.y*b.x); }
__device__ __forceinline__ cplx cadd(cplx a, cplx b){ return make_float2(a.x+b.x, a.y+b.y); }
__device__ __forceinline__ cplx csub(cplx a, cplx b){ return make_float2(a.x-b.x, a.y-b.y); }
template<int SIGN> __device__ __forceinline__ cplx rot90(cplx z){
  return (SIGN>0)? make_float2(-z.y,z.x) : make_float2(z.y,-z.x); }
__device__ __forceinline__ void lput(cplx* L, int i, cplx v){ L[sw(i)] = v; }
__device__ __forceinline__ cplx lget(const cplx* L, int i){ return L[sw(i)]; }

__device__ __forceinline__ int xcd_chunk(int bid, int nwg){
  return (bid & 7) * (nwg >> 3) + (bid >> 3);
}

// ---- in-place radix-8 stage: read all, barrier, write all, barrier.
template<int SIGN, int TPR, int M>
__device__ __forceinline__ void stage8_ip(cplx* X, int t) {
  constexpr int BPT = 256 / TPR;
  const float ang = (float)SIGN * 0.0030679615757712824f; // 2*pi/2048
  cplx a[BPT][8];
#pragma unroll
  for (int u = 0; u < BPT; ++u) {
    const int b = t + u * TPR;
#pragma unroll
    for (int k = 0; k < 8; ++k) a[u][k] = X[sw(b + 256 * k)];
  }
  __syncthreads();
#pragma unroll
  for (int u = 0; u < BPT; ++u) {
    const int b = t + u * TPR;
    const int i = b & (M - 1);
    const int jm = b - i;
    cplx a0=a[u][0], a1=a[u][1], a2=a[u][2], a3=a[u][3],
         a4=a[u][4], a5=a[u][5], a6=a[u][6], a7=a[u][7];
    cplx t0=cadd(a0,a4), t1=csub(a0,a4), t2=cadd(a2,a6), t3=rot90<SIGN>(csub(a2,a6));
    cplx E0=cadd(t0,t2), E2=csub(t0,t2), E1=cadd(t1,t3), E3=csub(t1,t3);
    cplx u0=cadd(a1,a5), u1=csub(a1,a5), u2=cadd(a3,a7), u3=rot90<SIGN>(csub(a3,a7));
    cplx O0=cadd(u0,u2), O2=csub(u0,u2), O1=cadd(u1,u3), O3=csub(u1,u3);
    const float hh = 0.70710678118654752440f;
    O1 = cmul(O1, make_float2(hh, (float)SIGN*hh));
    O2 = rot90<SIGN>(O2);
    O3 = cmul(O3, make_float2(-hh, (float)SIGN*hh));
    cplx y0=cadd(E0,O0), y4=csub(E0,O0);
    cplx y1=cadd(E1,O1), y5=csub(E1,O1);
    cplx y2=cadd(E2,O2), y6=csub(E2,O2);
    cplx y3=cadd(E3,O3), y7=csub(E3,O3);
    float sn, cs;
    __sincosf(ang * (float)jm, &sn, &cs);
    cplx w1 = make_float2(cs, sn);
    cplx w2 = cmul(w1,w1), w3 = cmul(w2,w1), w4 = cmul(w2,w2);
    cplx w5 = cmul(w3,w2), w6 = cmul(w3,w3), w7 = cmul(w4,w3);
    const int o = 8*jm + i;
    X[sw(o)]       = y0;
    X[sw(o+M)]     = cmul(y1,w1);
    X[sw(o+2*M)]   = cmul(y2,w2);
    X[sw(o+3*M)]   = cmul(y3,w3);
    X[sw(o+4*M)]   = cmul(y4,w4);
    X[sw(o+5*M)]   = cmul(y5,w5);
    X[sw(o+6*M)]   = cmul(y6,w6);
    X[sw(o+7*M)]   = cmul(y7,w7);
  }
  __syncthreads();
}

template<int SIGN, int TPR>
__device__ __forceinline__ void stage4_ip(cplx* X, int t){
  constexpr int QPT = 512 / TPR;
  cplx a[QPT][4];
#pragma unroll
  for (int u=0; u<QPT; ++u){
    const int b = t + u*TPR;
#pragma unroll
    for (int k=0;k<4;++k) a[u][k] = X[sw(b + 512*k)];
  }
  __syncthreads();
#pragma unroll
  for (int u=0; u<QPT; ++u){
    const int b = t + u*TPR;
    cplx a0=a[u][0], a1=a[u][1], a2=a[u][2], a3=a[u][3];
    cplx t0=cadd(a0,a2), t1=csub(a0,a2), t2=cadd(a1,a3), t3=rot90<SIGN>(csub(a1,a3));
    X[sw(b)]       = cadd(t0,t2);
    X[sw(b+512)]   = cadd(t1,t3);
    X[sw(b+1024)]  = csub(t0,t2);
    X[sw(b+1536)]  = csub(t1,t3);
  }
  __syncthreads();
}

template<int SIGN, int TPR>
__device__ __forceinline__ void fft_ip(cplx* X, int t){
  __syncthreads();
  stage8_ip<SIGN,TPR,1>(X,t);
  stage8_ip<SIGN,TPR,8>(X,t);
  stage8_ip<SIGN,TPR,64>(X,t);
  stage4_ip<SIGN,TPR>(X,t);
}

// ---- spectral unpack at one (kx,ky): a=F(ky,kx), b=F(-ky,-kx)
__device__ __forceinline__ void unpack_point(cplx a, cplx b,
    float kxv, float kyv, float kxp, float kyp,
    cplx& s1, cplx& s2, cplx& s3, cplx& s4) {
  cplx nh = make_float2(0.5f*(a.x + b.x),  0.5f*(a.y - b.y));
  cplx wh = make_float2(0.5f*(a.y + b.y), -0.5f*(a.x - b.x));
  float k2 = kxv*kxv + kyv*kyv;
  float pinv = (k2 > 1e-12f) ? (-1.0f/k2) : 0.0f;
  cplx ph = make_float2(wh.x*pinv, wh.y*pinv);
  s1 = make_float2(-kxp*ph.y - kyp*ph.x, kxp*ph.x - kyp*ph.y);
  s2 = make_float2(-kxp*nh.y - kyp*nh.x, kxp*nh.x - kyp*nh.y);
  s3 = make_float2(-kxp*wh.y - kyp*wh.x, kxp*wh.x - kyp*wh.y);
  float dnc = 0.001f * k2;
  cplx Ln = make_float2( kyp*ph.y + (ph.x - nh.x) - dnc*nh.x,
                        -kyp*ph.x + (ph.y - nh.y) - dnc*nh.y);
  cplx Lw = make_float2( kyp*nh.y + (ph.x - nh.x) - dnc*wh.x,
                        -kyp*nh.x + (ph.y - nh.y) - dnc*wh.y);
  s4 = make_float2(Ln.x - Lw.y, Ln.y + Lw.x);
}

// ---- kernels -------------------------------------------------------------

// 4 x-rows: load n,w, fft along y, transposed store -> out[ky][x] (f32)
__global__ void __launch_bounds__(512) k_fwd_pack_T(const float* __restrict__ nIn,
                                                    const float* __restrict__ wIn,
                                                    cplx* __restrict__ out) {
  __shared__ cplx L[4*NF];
  const int tid = threadIdx.x;
  const int lb = xcd_chunk(blockIdx.x, gridDim.x);
  const int xb = lb*4;
#pragma unroll
  for (int u=0; u<4; ++u){
    int f = tid + u*512;           // 0..2047
    int r = f >> 9;                // row 0..3
    int p = f & 511;               // float4 idx
    float4 nv = ((const float4*)(nIn + (size_t)(xb+r)*NF))[p];
    float4 wv = ((const float4*)(wIn + (size_t)(xb+r)*NF))[p];
    cplx* Lr = L + r*NF;
    lput(Lr, 4*p+0, make_float2(nv.x, wv.x));
    lput(Lr, 4*p+1, make_float2(nv.y, wv.y));
    lput(Lr, 4*p+2, make_float2(nv.z, wv.z));
    lput(Lr, 4*p+3, make_float2(nv.w, wv.w));
  }
  const int row = tid >> 7, t = tid & 127;
  fft_ip<-1,128>(L + row*NF, t);
  float4* o4 = (float4*)out;
#pragma unroll
  for (int u=0; u<8; ++u){
    int f = tid + u*512;           // 0..4095
    int ky = f >> 1;
    int xp = f & 1;
    cplx a = lget(L + (2*xp)*NF, ky);
    cplx b = lget(L + (2*xp+1)*NF, ky);
    o4[(size_t)ky*(NF/2) + lb*2 + xp] = make_float4(a.x,a.y,b.x,b.y);
  }
}

// rows kyA=b, kyB=(b==0?1024:2048-b): fftX both, unpack -> S1..S4 fp16 rows
// (pre-scaled by 1/N).
__global__ void __launch_bounds__(512) k_unpackS(const cplx* __restrict__ in,
                                                 ch* __restrict__ S1, ch* __restrict__ S2,
                                                 ch* __restrict__ S3, ch* __restrict__ S4) {
  __shared__ cplx F0[NF], F1[NF];
  const int tid = threadIdx.x;
  const int b = xcd_chunk(blockIdx.x, gridDim.x);   // 0..1023
  const int kyA = b;
  const int kyB = (b == 0) ? HALF : NF - b;
  const int half = tid >> 8;
  const int t = tid & 255;
  cplx* Fm = half ? F1 : F0;
  {
    const cplx* g = in + (size_t)(half ? kyB : kyA)*NF;
#pragma unroll
    for (int u=0; u<4; ++u){
      int p = t + u*256;
      float4 v = ((const float4*)g)[p];
      lput(Fm, 2*p,   make_float2(v.x,v.y));
      lput(Fm, 2*p+1, make_float2(v.z,v.w));
    }
    fft_ip<-1,256>(Fm, t);
  }
  const cplx* Fp = (b == 0) ? (const cplx*)Fm : (half ? F0 : F1);
  const int kyM = half ? kyB : kyA;
  const int sy = (kyM < HALF) ? kyM : kyM - NF;
  const float kyv = K0F * (float)sy;
  const float kyp = (kyM == HALF) ? 0.0f : kyv;
  const float sc = 1.0f/(float)NF;
  const size_t rbase = (size_t)kyM * NF;
#pragma unroll
  for (int u=0; u<8; ++u){
    int kx = t + u*256;
    int kx2 = (NF - kx) & (NF - 1);
    int sx = (kx < HALF) ? kx : kx - NF;
    float kxv = K0F * (float)sx;
    float kxp = (kx == HALF) ? 0.0f : kxv;
    cplx s1,s2,s3,s4;
    unpack_point(lget(Fm,kx), lget(Fp,kx2), kxv, kyv, kxp, kyp, s1,s2,s3,s4);
    S1[rbase+kx] = toh(make_float2(sc*s1.x, sc*s1.y));
    S2[rbase+kx] = toh(make_float2(sc*s2.x, sc*s2.y));
    S3[rbase+kx] = toh(make_float2(sc*s3.x, sc*s3.y));
    S4[rbase+kx] = toh(make_float2(sc*s4.x, sc*s4.y));
  }
}

// 4 rows x 2 arrays: ifft along contiguous dim (fp16 in, pre-scaled),
// transposed fp16 store -> T[x][ky] (one uint4 per x per block, dense)
__global__ void __launch_bounds__(512) k_inv2(const ch* __restrict__ in0,
                                              const ch* __restrict__ in1,
                                              ch* __restrict__ out0,
                                              ch* __restrict__ out1) {
  __shared__ cplx L[4*NF];
  const int tid = threadIdx.x;
  const int lb = xcd_chunk(blockIdx.x, gridDim.x);
  const ch* in = blockIdx.y ? in1 : in0;
  ch* out = blockIdx.y ? out1 : out0;
  const int rb = lb*4;
#pragma unroll
  for (int u=0; u<4; ++u){
    int f = tid + u*512;           // 0..2047
    int r = f >> 9, p = f & 511;   // 512 uint4 per fp16 row
    uint4 v = ((const uint4*)(in + (size_t)(rb+r)*NF))[p];
    cplx* Lr = L + r*NF;
    lput(Lr, 4*p+0, toc(*(ch*)&v.x));
    lput(Lr, 4*p+1, toc(*(ch*)&v.y));
    lput(Lr, 4*p+2, toc(*(ch*)&v.z));
    lput(Lr, 4*p+3, toc(*(ch*)&v.w));
  }
  const int row = tid >> 7, t = tid & 127;
  fft_ip<1,128>(L + row*NF, t);
  uint4* o16 = (uint4*)out;        // fp16 row = 512 uint4
#pragma unroll
  for (int u=0; u<4; ++u){
    int q = tid + u*512;           // output row (= x) 0..2047
    ch h0 = toh(lget(L + 0*NF, q));
    ch h1 = toh(lget(L + 1*NF, q));
    ch h2 = toh(lget(L + 2*NF, q));
    ch h3 = toh(lget(L + 3*NF, q));
    uint4 v;
    v.x = *(unsigned*)&h0; v.y = *(unsigned*)&h1;
    v.z = *(unsigned*)&h2; v.w = *(unsigned*)&h3;
    o16[(size_t)q*(NF/4) + lb] = v;
  }
}

// 1 x-row: 3x ifft along ky (dphi in regs), bracket, fwd fft -> BR[x][ky']
// fp16, skipping stores of the my-masked middle third.
__global__ void __launch_bounds__(256) k_bracket(const ch* __restrict__ T1,
                                                 const ch* __restrict__ T2,
                                                 const ch* __restrict__ T3,
                                                 ch* __restrict__ out) {
  __shared__ cplx A[NF];
  const int t = threadIdx.x;
  const size_t base = (size_t)blockIdx.x * NF;
#pragma unroll
  for (int u=0; u<2; ++u){
    int p = t + u*256;
    uint4 v = ((const uint4*)(T1 + base))[p];
    lput(A, 4*p+0, toc(*(ch*)&v.x)); lput(A, 4*p+1, toc(*(ch*)&v.y));
    lput(A, 4*p+2, toc(*(ch*)&v.z)); lput(A, 4*p+3, toc(*(ch*)&v.w));
  }
  fft_ip<1,256>(A, t);                  // (dphix,dphiy)*N
  cplx dphi[8];
#pragma unroll
  for (int u=0; u<8; ++u) dphi[u] = lget(A, t + u*256);
  __syncthreads();
#pragma unroll
  for (int u=0; u<2; ++u){
    int p = t + u*256;
    uint4 v = ((const uint4*)(T2 + base))[p];
    lput(A, 4*p+0, toc(*(ch*)&v.x)); lput(A, 4*p+1, toc(*(ch*)&v.y));
    lput(A, 4*p+2, toc(*(ch*)&v.z)); lput(A, 4*p+3, toc(*(ch*)&v.w));
  }
  fft_ip<1,256>(A, t);                  // (dnx,dny)*N
  float jn[8];
#pragma unroll
  for (int u=0; u<8; ++u){
    cplx dd = lget(A, t + u*256);
    jn[u] = dphi[u].x*dd.y - dphi[u].y*dd.x;
  }
  __syncthreads();
#pragma unroll
  for (int u=0; u<2; ++u){
    int p = t + u*256;
    uint4 v = ((const uint4*)(T3 + base))[p];
    lput(A, 4*p+0, toc(*(ch*)&v.x)); lput(A, 4*p+1, toc(*(ch*)&v.y));
    lput(A, 4*p+2, toc(*(ch*)&v.z)); lput(A, 4*p+3, toc(*(ch*)&v.w));
  }
  fft_ip<1,256>(A, t);                  // (dwx,dwy)*N
  const float sc2 = 1.0f/((float)NF*(float)NF);
#pragma unroll
  for (int u=0; u<8; ++u){
    int c = t + u*256;
    cplx dd = lget(A, c);
    float jw = dphi[u].x*dd.y - dphi[u].y*dd.x;
    lput(A, c, make_float2(sc2*jn[u], sc2*jw));   // own-slot r/w
  }
  fft_ip<-1,256>(A, t);                 // fft(j_n + i*j_w) along y
  uint4* o16 = (uint4*)(out + base);
#pragma unroll
  for (int u=0; u<2; ++u){
    int p = t + u*256;                  // uint4 covers ky' 4p..4p+3
    if (p <= 170 || p >= 341) {         // skip fully-masked [683,1365]
      ch h0 = toh(lget(A, 4*p+0));
      ch h1 = toh(lget(A, 4*p+1));
      ch h2 = toh(lget(A, 4*p+2));
      ch h3 = toh(lget(A, 4*p+3));
      uint4 v;
      v.x = *(unsigned*)&h0; v.y = *(unsigned*)&h1;
      v.z = *(unsigned*)&h2; v.w = *(unsigned*)&h3;
      o16[p] = v;
    }
  }
}

// 4 ky'-columns: fftX, 2/3 mask * (1/N), ifftX, transposed fp16 write.
// Fully-masked slabs: write zeros only.
__global__ void __launch_bounds__(512) k_slabX(const ch* __restrict__ in,
                                               ch* __restrict__ out) {
  __shared__ cplx L[4*NF];
  const int tid = threadIdx.x;
  const int lb = xcd_chunk(blockIdx.x, gridDim.x);
  const int cb = lb*4;
  if (cb >= 684 && cb <= 1360) {        // all 4 ky' masked
    uint4 z; z.x = z.y = z.z = z.w = 0u;
#pragma unroll
    for (int u=0; u<4; ++u){
      int x = tid + u*512;
      *(uint4*)(out + (size_t)x*NF + cb) = z;
    }
    return;
  }
#pragma unroll
  for (int u=0; u<4; ++u){
    int x = tid + u*512;           // 0..2047
    uint4 v = *(const uint4*)(in + (size_t)x*NF + cb);
    lput(L + 0*NF, x, toc(*(ch*)&v.x));
    lput(L + 1*NF, x, toc(*(ch*)&v.y));
    lput(L + 2*NF, x, toc(*(ch*)&v.z));
    lput(L + 3*NF, x, toc(*(ch*)&v.w));
  }
  const int row = tid >> 7, t = tid & 127;
  fft_ip<-1,128>(L + row*NF, t);
  const float sc = 1.0f/(float)NF;
#pragma unroll
  for (int v2=0; v2<16; ++v2){
    int g = tid + v2*512;          // 0..8191
    int c = g >> 11, kk = g & 2047;
    int ky = cb + c;
    int sy = (ky < HALF) ? ky : ky - NF;
    int sx = (kk < HALF) ? kk : kk - NF;
    float m = (((sy<0?-sy:sy) <= DEAL_LIM) && ((sx<0?-sx:sx) <= DEAL_LIM)) ? sc : 0.0f;
    cplx z = lget(L + c*NF, kk);
    lput(L + c*NF, kk, make_float2(m*z.x, m*z.y));   // own-slot r/w
  }
  fft_ip<1,128>(L + row*NF, t);
#pragma unroll
  for (int u=0; u<4; ++u){
    int x = tid + u*512;
    ch h0 = toh(lget(L + 0*NF, x));
    ch h1 = toh(lget(L + 1*NF, x));
    ch h2 = toh(lget(L + 2*NF, x));
    ch h3 = toh(lget(L + 3*NF, x));
    uint4 v;
    v.x = *(unsigned*)&h0; v.y = *(unsigned*)&h1;
    v.z = *(unsigned*)&h2; v.w = *(unsigned*)&h3;
    *(uint4*)(out + (size_t)x*NF + cb) = v;
  }
}

// 1 x-row: ifft ADVt (adv in regs), ifft T4, combine -> dn,dw (f32)
__global__ void __launch_bounds__(256) k_final(const ch* __restrict__ ADVt,
                                               const ch* __restrict__ T4,
                                               float* __restrict__ outF) {
  __shared__ cplx A[NF];
  const int t = threadIdx.x;
  const size_t base = (size_t)blockIdx.x * NF;
#pragma unroll
  for (int u=0; u<2; ++u){
    int p = t + u*256;
    uint4 v = ((const uint4*)(ADVt + base))[p];
    lput(A, 4*p+0, toc(*(ch*)&v.x)); lput(A, 4*p+1, toc(*(ch*)&v.y));
    lput(A, 4*p+2, toc(*(ch*)&v.z)); lput(A, 4*p+3, toc(*(ch*)&v.w));
  }
  fft_ip<1,256>(A, t);                  // adv*N
  cplx adv[8];
#pragma unroll
  for (int u=0; u<8; ++u) adv[u] = lget(A, t + u*256);
  __syncthreads();
#pragma unroll
  for (int u=0; u<2; ++u){
    int p = t + u*256;
    uint4 v = ((const uint4*)(T4 + base))[p];
    lput(A, 4*p+0, toc(*(ch*)&v.x)); lput(A, 4*p+1, toc(*(ch*)&v.y));
    lput(A, 4*p+2, toc(*(ch*)&v.z)); lput(A, 4*p+3, toc(*(ch*)&v.w));
  }
  fft_ip<1,256>(A, t);                  // (Ln,Lw)*N
  const float sc = 1.0f/(float)NF;
  const size_t NSQ = (size_t)NF*NF;
#pragma unroll
  for (int u=0; u<8; ++u){
    int c = t + u*256;
    cplx Lv = lget(A, c);
    outF[base + c]       = sc*(Lv.x - adv[u].x);   // dn
    outF[NSQ + base + c] = sc*(Lv.y - adv[u].y);   // dw
  }
}

extern "C" void kernel_launch(void* const* d_in, const int* in_sizes, int n_in,
                              void* d_out, int out_size, void* d_ws, size_t ws_size,
                              hipStream_t stream) {
  const float* nIn = (const float*)d_in[0];
  const float* wIn = (const float*)d_in[1];
  float* outF = (float*)d_out;

  const size_t B  = (size_t)NF * NF * sizeof(cplx);    // 33.5 MB
  const size_t Bh = (size_t)NF * NF * sizeof(ch);      // 16.75 MB
  char* ws = (char*)d_ws;
  cplx* W    = (cplx*)(ws);                 // slot0
  ch*   S1   = (ch*)(ws + 1*B);             // slot1 (later ADVt)
  ch*   S2   = (ch*)(ws + 1*B + Bh);
  ch*   S3   = (ch*)(ws + 2*B);             // slot2
  ch*   S4   = (ch*)(ws + 2*B + Bh);
  ch*   T1   = (ch*)(ws + 3*B);             // slot3
  ch*   T2   = (ch*)(ws + 3*B + Bh);
  ch*   T3   = (ch*)(ws + 4*B);             // slot4
  ch*   T4   = (ch*)(ws + 4*B + Bh);
  ch*   ADVt = (ch*)(ws + 1*B);             // slot1 (S1,S2 dead by then)
  ch*   BR   = (ch*)d_out;                  // scratch until k_final overwrites

  // forward pass 1 (along y) with transposed store
  k_fwd_pack_T <<<512, 512, 0, stream>>>(nIn, wIn, W);

  // forward pass 2 + unpack -> S1..S4 (fp16, 1/N)
  k_unpackS <<<1024, 512, 0, stream>>>(W, S1, S2, S3, S4);

  // ifft along kx + transposed fp16 store
  k_inv2 <<<dim3(512,2), 512, 0, stream>>>(S1, S2, T1, T2);
  k_inv2 <<<dim3(512,2), 512, 0, stream>>>(S3, S4, T3, T4);

  // bracket (finishes ifftY) + fwd fftY -> BR [x][ky'] fp16 (masked skipped)
  k_bracket <<<NF, 256, 0, stream>>>(T1, T2, T3, BR);

  // fftX + dealias + ifftX fused, transposed fp16 write -> ADVt [x][ky']
  k_slabX <<<512, 512, 0, stream>>>(BR, ADVt);

  // final: ifftY of ADVt & T4, combine -> d_out
  k_final <<<NF, 256, 0, stream>>>(ADVt, T4, outF);
}